// Round 7
// baseline (611.040 us; speedup 1.0000x reference)
//
#include <hip/hip_runtime.h>
#include <stdint.h>

#define VOCAB 50257
#define NP2   50432      // padded vocab = 197*256
#define H     256
#define BS    4096       // B*S tokens
#define K2    512        // hi/lo interleaved K
#define SIB   0.0625f    // 1/sqrt(256)

typedef __attribute__((ext_vector_type(8))) _Float16 f16x8;
typedef __attribute__((ext_vector_type(4))) float f32x4;

__device__ __forceinline__ void gload_lds16(const void* g, void* l) {
  __builtin_amdgcn_global_load_lds(
      (const __attribute__((address_space(1))) void*)g,
      (__attribute__((address_space(3))) void*)l, 16, 0, 0);
}

// ---------------- sib projections: polW@sib0, polW@sib1, childW@sib0, childW@sib1
__global__ __launch_bounds__(256) void k_sib(const float* __restrict__ pol_W1,
                                             const float* __restrict__ child_W,
                                             const float* __restrict__ sib_emb,
                                             float* __restrict__ sibproj) {
  const int b = blockIdx.x;  // 0..3
  const float* Wm = (b < 2) ? pol_W1 : child_W;
  const float* v = sib_emb + (b & 1) * H;
  const int h = threadIdx.x;
  const float4* wr = (const float4*)(Wm + h * H);
  const float4* vr = (const float4*)v;
  float acc = 0.f;
  for (int i = 0; i < 64; ++i) {
    float4 w = wr[i], x = vr[i];
    acc += w.x * x.x + w.y * x.y + w.z * x.z + w.w * x.w;
  }
  sibproj[b * H + h] = acc;
}

// ---------------- out_W f32 -> interleaved f16 hi/lo (lo pre-scaled by 64)
__global__ __launch_bounds__(256) void k_conv(const float* __restrict__ W,
                                              _Float16* __restrict__ B2) {
  const int64_t nit = (int64_t)NP2 * 64;
  for (int64_t i = (int64_t)blockIdx.x * blockDim.x + threadIdx.x; i < nit;
       i += (int64_t)gridDim.x * blockDim.x) {
    const int v = (int)(i >> 6);
    const int h4 = ((int)i & 63) * 4;
    float4 w;
    if (v < VOCAB) w = *(const float4*)(W + (int64_t)v * H + h4);
    else w = make_float4(0.f, 0.f, 0.f, 0.f);
    float a[4] = {w.x, w.y, w.z, w.w};
    _Float16 o[8];
#pragma unroll
    for (int j = 0; j < 4; ++j) {
      _Float16 hi = (_Float16)a[j];
      float lo = (a[j] - (float)hi) * 64.f;
      o[2 * j] = hi;
      o[2 * j + 1] = (_Float16)lo;
    }
    *(f16x8*)(B2 + (int64_t)v * K2 + h4 * 2) = *(f16x8*)o;
  }
}

// ---------------- per-token tree -> pooled -> A2 (f16, dup columns: [a, a/64])
#define MATVEC(Wp, SRC, ACC)                                                      \
  do {                                                                            \
    _Pragma("unroll") for (int j = 0; j < 4; ++j)                                 \
        _Pragma("unroll") for (int tt = 0; tt < 4; ++tt) ACC[j][tt] = 0.f;        \
    _Pragma("unroll 2") for (int e4 = 0; e4 < 64; ++e4) {                         \
      float4 wv[4], sv[4];                                                        \
      _Pragma("unroll") for (int j = 0; j < 4; ++j)                               \
          wv[j] = *(const float4*)(Wp + (hg + 64 * j) * H + e4 * 4);              \
      _Pragma("unroll") for (int tt = 0; tt < 4; ++tt)                            \
          sv[tt] = *(const float4*)&SRC[tg * 4 + tt][e4 * 4];                     \
      _Pragma("unroll") for (int j = 0; j < 4; ++j)                               \
          _Pragma("unroll") for (int tt = 0; tt < 4; ++tt)                        \
              ACC[j][tt] += wv[j].x * sv[tt].x + wv[j].y * sv[tt].y +             \
                            wv[j].z * sv[tt].z + wv[j].w * sv[tt].w;              \
    }                                                                             \
  } while (0)

#define REDUCE_TO_X(slot)                                                \
  do {                                                                   \
    const int rt = tid >> 4, rl = tid & 15;                              \
    float part = 0.f;                                                    \
    _Pragma("unroll") for (int i = 0; i < 16; ++i) part +=               \
        ZW[rt][rl + 16 * i];                                             \
    part += __shfl_xor(part, 1, 16);                                     \
    part += __shfl_xor(part, 2, 16);                                     \
    part += __shfl_xor(part, 4, 16);                                     \
    part += __shfl_xor(part, 8, 16);                                     \
    if (rl == 0) X[slot][rt] = part + b2;                                \
  } while (0)

__global__ __launch_bounds__(256) void k_pooled(
    const int* __restrict__ tokens, const float* __restrict__ emb,
    const float* __restrict__ proj_W, const float* __restrict__ proj_b,
    const float* __restrict__ child_W, const float* __restrict__ child_b,
    const float* __restrict__ sib_emb, const float* __restrict__ depth_emb,
    const float* __restrict__ pol_W1, const float* __restrict__ pol_b1,
    const float* __restrict__ pol_w2, const float* __restrict__ pol_b2,
    const float* __restrict__ sibproj, _Float16* __restrict__ A2) {
  __shared__ float IN[16][256];
  __shared__ float H0[16][256];
  __shared__ float B0s[16][256];
  __shared__ float ZW[16][264];
  __shared__ float X[3][16];
  __shared__ int TOK[16];
  const int tid = threadIdx.x;
  const int hg = tid & 63;   // h = hg + 64*j
  const int tg = tid >> 6;   // tokens tg*4 .. tg*4+3
  const int t0 = blockIdx.x * 16;
  const float b2 = pol_b2[0];

  float sibs[4];
#pragma unroll
  for (int j = 0; j < 4; ++j) {
    const int hj = hg + 64 * j;
    sibs[j] = SIB * (sib_emb[hj] + sib_emb[H + hj]);
  }

  if (tid < 16) TOK[tid] = tokens[t0 + tid];
  __syncthreads();
  for (int t = 0; t < 16; ++t) IN[t][tid] = emb[(int64_t)TOK[t] * H + tid];
  __syncthreads();

  float acc[4][4], sum[4][4];

  // h0 = proj_W @ emb + proj_b
  MATVEC(proj_W, IN, acc);
#pragma unroll
  for (int j = 0; j < 4; ++j) {
    const int hj = hg + 64 * j;
    const float pb = proj_b[hj];
#pragma unroll
    for (int tt = 0; tt < 4; ++tt) {
      const float h0v = acc[j][tt] + pb;
      H0[tg * 4 + tt][hj] = h0v;
      sum[j][tt] = h0v;
    }
  }
  __syncthreads();

  // depth-0 policy
  MATVEC(pol_W1, H0, acc);
#pragma unroll
  for (int j = 0; j < 4; ++j) {
    const int hj = hg + 64 * j;
    const float pb1 = pol_b1[hj], de0 = depth_emb[hj], w2 = pol_w2[hj];
#pragma unroll
    for (int tt = 0; tt < 4; ++tt) {
      const float z = tanhf(acc[j][tt] + pb1 + de0);
      ZW[tg * 4 + tt][hj] = z * w2;
    }
  }
  __syncthreads();
  REDUCE_TO_X(0);
  __syncthreads();

  // depth-0 children base
  MATVEC(child_W, H0, acc);
#pragma unroll
  for (int j = 0; j < 4; ++j) {
    const int hj = hg + 64 * j;
    const float cb = child_b[hj];
#pragma unroll
    for (int tt = 0; tt < 4; ++tt) {
      const float base0 = tanhf(acc[j][tt] + cb);
      B0s[tg * 4 + tt][hj] = base0;
      const float g0 = (X[0][tg * 4 + tt] >= 0.f) ? 1.f : 0.f;
      sum[j][tt] += g0 * (2.f * base0 + sibs[j]);
    }
  }
  __syncthreads();

  // depth-1 policy: polW@base (+ precomputed polW@sib_k)
  float accP[4][4];
  MATVEC(pol_W1, B0s, accP);
#pragma unroll
  for (int k = 0; k < 2; ++k) {
#pragma unroll
    for (int j = 0; j < 4; ++j) {
      const int hj = hg + 64 * j;
      const float pb1 = pol_b1[hj], de1 = depth_emb[H + hj], w2 = pol_w2[hj];
      const float ps = sibproj[k * H + hj];
#pragma unroll
      for (int tt = 0; tt < 4; ++tt) {
        const float z = tanhf(accP[j][tt] + SIB * ps + pb1 + de1);
        ZW[tg * 4 + tt][hj] = z * w2;
      }
    }
    __syncthreads();
    if (k == 0) REDUCE_TO_X(1); else REDUCE_TO_X(2);
    __syncthreads();
  }

  // depth-1 children base + final pooled
  MATVEC(child_W, B0s, acc);
#pragma unroll
  for (int j = 0; j < 4; ++j) {
    const int hj = hg + 64 * j;
    const float cb = child_b[hj];
    const float cs0 = sibproj[2 * H + hj], cs1 = sibproj[3 * H + hj];
#pragma unroll
    for (int tt = 0; tt < 4; ++tt) {
      const int t = tg * 4 + tt;
      const float g0 = (X[0][t] >= 0.f) ? 1.f : 0.f;
      const float m0 = (g0 > 0.f && X[1][t] >= 0.f) ? 1.f : 0.f;
      const float m1 = (g0 > 0.f && X[2][t] >= 0.f) ? 1.f : 0.f;
      const float bk0 = tanhf(acc[j][tt] + SIB * cs0 + cb);
      const float bk1 = tanhf(acc[j][tt] + SIB * cs1 + cb);
      float s = sum[j][tt] + m0 * (2.f * bk0 + sibs[j]) + m1 * (2.f * bk1 + sibs[j]);
      const float cnt = 1.f + 2.f * g0 + 2.f * (m0 + m1);
      const float pooled = s / (cnt + 1e-8f);
      union { _Float16 hh[2]; uint32_t u; } pk;
      pk.hh[0] = (_Float16)pooled;
      pk.hh[1] = (_Float16)(pooled * 0.015625f);  // matches 64x-scaled lo plane
      *(uint32_t*)(A2 + (int64_t)(t0 + t) * K2 + 2 * hj) = pk.u;
    }
  }
}

// ---------------- big GEMM: C[4096][50257] = A2[4096][512] * B2[50432][512]^T + out_b
// 256x256 tile, 8 waves, BK=32, 4-buffer LDS ring (4x32KB), 8-phase-style
// schedule: compute tile t from buf[t&3], stage tile t+3 into buf[(t+3)&3]
// (held t-1, consumed -> race-free). Per K-tile: 2 phases of
// {ds_read 4-8 x b128 || 2 block-wide gload_lds -> barrier -> setprio(1) ->
//  16 MFMA -> setprio(0) -> barrier}; vmcnt counted ONCE per K-tile (8 steady,
// 8->4->0 tail), never drained mid-loop. BK=32 rows (64B) are naturally
// bank-conflict-free for both linear gload-write and fragment reads.
// Grid 3152 = 8 XCD x 394, n-outer/m-inner per XCD. Epilogue: R6-verified
// LDS transpose -> contiguous 256B nontemporal stores.
__global__ __launch_bounds__(512, 2) void k_gemm(const _Float16* __restrict__ A2,
                                                 const _Float16* __restrict__ B2,
                                                 const float* __restrict__ out_b,
                                                 float* __restrict__ C) {
  extern __shared__ __align__(16) char smem[];  // 131072 B = 4 x (A 16KB + B 16KB)
  const int tid = threadIdx.x;
  const int lane = tid & 63;
  const int w = tid >> 6;       // 0..7
  const int wr = w >> 2;        // 0..1 : row-half
  const int wc = w & 3;         // 0..3 : col-quarter
  const int wg = blockIdx.x;
  const int idx = (wg & 7) * 394 + (wg >> 3);
  const int m0 = (idx & 15) * 256;
  const int n0 = (idx >> 4) * 256;
  f32x4 acc[8][4] = {};

  // staging: block-wide gload = 8KB = 128 rows x 32 f16; wave w rows w*16+..
  const int srow = w * 16 + (lane >> 2);    // 0..127 within half
  const int sgr = (lane & 3) * 8;           // granule (f16 offset)
  const _Float16* gAb = A2 + (int64_t)(m0 + srow) * K2 + sgr;
  const _Float16* gBb = B2 + (int64_t)(n0 + srow) * K2 + sgr;

  const int fr = lane & 15;
  const int g = lane >> 4;                  // 0..3 : K-octet

#define BAR() asm volatile("s_barrier" ::: "memory")
#define SCB() __builtin_amdgcn_sched_barrier(0)
  // stage half h (rows h*128..h*128+127) of K-tile t into buf[t&3]
#define STAGE32(t, h)                                                         \
  do {                                                                        \
    _Float16* dst = (_Float16*)(smem + ((t) & 3) * 32768);                    \
    gload_lds16(gAb + (int64_t)(h) * 128 * K2 + (t) * 32,                     \
                dst + ((h) * 128 + srow) * 32 + sgr);                         \
    gload_lds16(gBb + (int64_t)(h) * 128 * K2 + (t) * 32,                     \
                dst + 8192 + ((h) * 128 + srow) * 32 + sgr);                  \
  } while (0)

  // prologue: stage tiles 0,1,2 (12 loads/thread); drain tile 0 -> vmcnt(8)
  STAGE32(0, 0); STAGE32(0, 1);
  STAGE32(1, 0); STAGE32(1, 1);
  STAGE32(2, 0); STAGE32(2, 1);
  asm volatile("s_waitcnt vmcnt(8)" ::: "memory");
  BAR();

  for (int t = 0; t < 16; ++t) {
    const _Float16* At = (const _Float16*)(smem + (t & 3) * 32768);
    const _Float16* Bt = At + 8192;
    // ---- phase 0: bf(4) + af(mi 0..3), stage half0 of t+3, 16 MFMA
    f16x8 bf[4], af[4];
#pragma unroll
    for (int ni = 0; ni < 4; ++ni)
      bf[ni] = *(const f16x8*)(Bt + (wc * 64 + ni * 16 + fr) * 32 + g * 8);
#pragma unroll
    for (int i = 0; i < 4; ++i)
      af[i] = *(const f16x8*)(At + (wr * 128 + i * 16 + fr) * 32 + g * 8);
    if (t < 13) STAGE32(t + 3, 0);
    SCB();
    BAR();
    SCB();
    __builtin_amdgcn_s_setprio(1);
#pragma unroll
    for (int i = 0; i < 4; ++i)
#pragma unroll
      for (int ni = 0; ni < 4; ++ni)
        acc[i][ni] = __builtin_amdgcn_mfma_f32_16x16x32_f16(af[i], bf[ni], acc[i][ni], 0, 0, 0);
    __builtin_amdgcn_s_setprio(0);
    SCB();
    BAR();
    // ---- phase 1: af(mi 4..7), stage half1 of t+3, 16 MFMA, tile-t vmcnt
    f16x8 ag[4];
#pragma unroll
    for (int i = 0; i < 4; ++i)
      ag[i] = *(const f16x8*)(At + (wr * 128 + (4 + i) * 16 + fr) * 32 + g * 8);
    if (t < 13) STAGE32(t + 3, 1);
    SCB();
    BAR();
    SCB();
    __builtin_amdgcn_s_setprio(1);
#pragma unroll
    for (int i = 0; i < 4; ++i)
#pragma unroll
      for (int ni = 0; ni < 4; ++ni)
        acc[4 + i][ni] = __builtin_amdgcn_mfma_f32_16x16x32_f16(ag[i], bf[ni], acc[4 + i][ni], 0, 0, 0);
    __builtin_amdgcn_s_setprio(0);
    SCB();
    // ensure tile t+1 landed (all waves) before its reads after next barrier
    if (t < 13) asm volatile("s_waitcnt vmcnt(8)" ::: "memory");
    else if (t == 13) asm volatile("s_waitcnt vmcnt(4)" ::: "memory");
    else if (t == 14) asm volatile("s_waitcnt vmcnt(0)" ::: "memory");
    BAR();
  }

  // ---- epilogue (R6-verified): 4 rounds of 64x256 transpose + streamed stores
  float biasn[4];
#pragma unroll
  for (int ni = 0; ni < 4; ++ni) {
    const int gn = n0 + wc * 64 + ni * 16 + fr;
    biasn[ni] = (gn < VOCAB) ? out_b[gn] : 0.f;
  }
  float* L = (float*)smem;  // [64][260]
#pragma unroll
  for (int c2 = 0; c2 < 4; ++c2) {
#pragma unroll
    for (int dmi = 0; dmi < 2; ++dmi) {
      const int mi = c2 * 2 + dmi;
#pragma unroll
      for (int ni = 0; ni < 4; ++ni) {
        const int lcol = wc * 64 + ni * 16 + fr;
#pragma unroll
        for (int r = 0; r < 4; ++r) {
          const int lrow = wr * 32 + dmi * 16 + g * 4 + r;
          L[lrow * 260 + lcol] = acc[mi][ni][r] + biasn[ni];
        }
      }
    }
    __syncthreads();
#pragma unroll
    for (int s = 0; s < 8; ++s) {
      const int lr = w + 8 * s;
      const int gr = m0 + (lr >> 5) * 128 + c2 * 32 + (lr & 31);
      float* Crow = C + (int64_t)gr * VOCAB + n0;
#pragma unroll
      for (int hh = 0; hh < 4; ++hh) {
        const int c = hh * 64 + lane;
        const float v = L[lr * 260 + c];
        if (n0 + c < VOCAB) __builtin_nontemporal_store(v, Crow + c);
      }
    }
    __syncthreads();
  }
#undef STAGE32
#undef BAR
#undef SCB
}

extern "C" void kernel_launch(void* const* d_in, const int* in_sizes, int n_in,
                              void* d_out, int out_size, void* d_ws, size_t ws_size,
                              hipStream_t stream) {
  const int* tokens = (const int*)d_in[0];
  const float* embedding = (const float*)d_in[1];
  const float* proj_W = (const float*)d_in[2];
  const float* proj_b = (const float*)d_in[3];
  const float* child_W = (const float*)d_in[4];
  const float* child_b = (const float*)d_in[5];
  const float* sib_emb = (const float*)d_in[6];
  const float* depth_emb = (const float*)d_in[7];
  const float* pol_W1 = (const float*)d_in[8];
  const float* pol_b1 = (const float*)d_in[9];
  const float* pol_w2 = (const float*)d_in[10];
  const float* pol_b2 = (const float*)d_in[11];
  const float* out_W = (const float*)d_in[12];
  const float* out_b = (const float*)d_in[13];
  float* C = (float*)d_out;
  char* ws = (char*)d_ws;
  _Float16* B2 = (_Float16*)ws;                              // 50432*512*2 = 51,642,368 B
  _Float16* A2 = (_Float16*)(ws + 51642368);                 // 4096*512*2  =  4,194,304 B
  float* sibproj = (float*)(ws + 51642368 + 4194304);        // 4*256*4 = 4 KB

  (void)hipFuncSetAttribute((const void*)k_gemm,
                            hipFuncAttributeMaxDynamicSharedMemorySize, 131072);

  k_sib<<<4, 256, 0, stream>>>(pol_W1, child_W, sib_emb, sibproj);
  k_conv<<<2048, 256, 0, stream>>>(out_W, B2);
  k_pooled<<<256, 256, 0, stream>>>(tokens, embedding, proj_W, proj_b, child_W,
                                    child_b, sib_emb, depth_emb, pol_W1, pol_b1,
                                    pol_w2, pol_b2, sibproj, A2);
  k_gemm<<<3152, 512, 131072, stream>>>(A2, B2, out_b, C);
}

// Round 8
// 551.272 us; speedup vs baseline: 1.1084x; 1.1084x over previous
//
#include <hip/hip_runtime.h>
#include <stdint.h>

#define VOCAB 50257
#define NP    50304      // padded vocab = 393*128
#define H     256
#define BS    4096       // B*S tokens
#define K3    256        // single-f16 K (A-rounding ~= B-rounding ~5e-4 each)
#define SIB   0.0625f    // 1/sqrt(256)

typedef __attribute__((ext_vector_type(8))) _Float16 f16x8;
typedef __attribute__((ext_vector_type(4))) float f32x4;

__device__ __forceinline__ void gload_lds16(const void* g, void* l) {
  __builtin_amdgcn_global_load_lds(
      (const __attribute__((address_space(1))) void*)g,
      (__attribute__((address_space(3))) void*)l, 16, 0, 0);
}

// ---------------- sib projections: polW@sib0, polW@sib1, childW@sib0, childW@sib1
__global__ __launch_bounds__(256) void k_sib(const float* __restrict__ pol_W1,
                                             const float* __restrict__ child_W,
                                             const float* __restrict__ sib_emb,
                                             float* __restrict__ sibproj) {
  const int b = blockIdx.x;  // 0..3
  const float* Wm = (b < 2) ? pol_W1 : child_W;
  const float* v = sib_emb + (b & 1) * H;
  const int h = threadIdx.x;
  const float4* wr = (const float4*)(Wm + h * H);
  const float4* vr = (const float4*)v;
  float acc = 0.f;
  for (int i = 0; i < 64; ++i) {
    float4 w = wr[i], x = vr[i];
    acc += w.x * x.x + w.y * x.y + w.z * x.z + w.w * x.w;
  }
  sibproj[b * H + h] = acc;
}

// ---------------- out_W f32 -> f16 [NP][256] (pad rows zero)
__global__ __launch_bounds__(256) void k_conv(const float* __restrict__ W,
                                              _Float16* __restrict__ B2) {
  const int64_t nit = (int64_t)NP * 32;  // 8 f16 per iter
  for (int64_t i = (int64_t)blockIdx.x * blockDim.x + threadIdx.x; i < nit;
       i += (int64_t)gridDim.x * blockDim.x) {
    const int v = (int)(i >> 5);
    const int h8 = ((int)i & 31) * 8;
    float4 w0, w1;
    if (v < VOCAB) {
      w0 = *(const float4*)(W + (int64_t)v * H + h8);
      w1 = *(const float4*)(W + (int64_t)v * H + h8 + 4);
    } else {
      w0 = make_float4(0.f, 0.f, 0.f, 0.f);
      w1 = w0;
    }
    _Float16 o[8] = {(_Float16)w0.x, (_Float16)w0.y, (_Float16)w0.z, (_Float16)w0.w,
                     (_Float16)w1.x, (_Float16)w1.y, (_Float16)w1.z, (_Float16)w1.w};
    *(f16x8*)(B2 + (int64_t)v * K3 + h8) = *(f16x8*)o;
  }
}

// ---------------- per-token tree -> pooled -> A2 (f16 [4096][256])
#define MATVEC(Wp, SRC, ACC)                                                      \
  do {                                                                            \
    _Pragma("unroll") for (int j = 0; j < 4; ++j)                                 \
        _Pragma("unroll") for (int tt = 0; tt < 4; ++tt) ACC[j][tt] = 0.f;        \
    _Pragma("unroll 2") for (int e4 = 0; e4 < 64; ++e4) {                         \
      float4 wv[4], sv[4];                                                        \
      _Pragma("unroll") for (int j = 0; j < 4; ++j)                               \
          wv[j] = *(const float4*)(Wp + (hg + 64 * j) * H + e4 * 4);              \
      _Pragma("unroll") for (int tt = 0; tt < 4; ++tt)                            \
          sv[tt] = *(const float4*)&SRC[tg * 4 + tt][e4 * 4];                     \
      _Pragma("unroll") for (int j = 0; j < 4; ++j)                               \
          _Pragma("unroll") for (int tt = 0; tt < 4; ++tt)                        \
              ACC[j][tt] += wv[j].x * sv[tt].x + wv[j].y * sv[tt].y +             \
                            wv[j].z * sv[tt].z + wv[j].w * sv[tt].w;              \
    }                                                                             \
  } while (0)

#define REDUCE_TO_X(slot)                                                \
  do {                                                                   \
    const int rt = tid >> 4, rl = tid & 15;                              \
    float part = 0.f;                                                    \
    _Pragma("unroll") for (int i = 0; i < 16; ++i) part +=               \
        ZW[rt][rl + 16 * i];                                             \
    part += __shfl_xor(part, 1, 16);                                     \
    part += __shfl_xor(part, 2, 16);                                     \
    part += __shfl_xor(part, 4, 16);                                     \
    part += __shfl_xor(part, 8, 16);                                     \
    if (rl == 0) X[slot][rt] = part + b2;                                \
  } while (0)

__global__ __launch_bounds__(256) void k_pooled(
    const int* __restrict__ tokens, const float* __restrict__ emb,
    const float* __restrict__ proj_W, const float* __restrict__ proj_b,
    const float* __restrict__ child_W, const float* __restrict__ child_b,
    const float* __restrict__ sib_emb, const float* __restrict__ depth_emb,
    const float* __restrict__ pol_W1, const float* __restrict__ pol_b1,
    const float* __restrict__ pol_w2, const float* __restrict__ pol_b2,
    const float* __restrict__ sibproj, _Float16* __restrict__ A2) {
  __shared__ float IN[16][256];
  __shared__ float H0[16][256];
  __shared__ float B0s[16][256];
  __shared__ float ZW[16][264];
  __shared__ float X[3][16];
  __shared__ int TOK[16];
  const int tid = threadIdx.x;
  const int hg = tid & 63;   // h = hg + 64*j
  const int tg = tid >> 6;   // tokens tg*4 .. tg*4+3
  const int t0 = blockIdx.x * 16;
  const float b2 = pol_b2[0];

  float sibs[4];
#pragma unroll
  for (int j = 0; j < 4; ++j) {
    const int hj = hg + 64 * j;
    sibs[j] = SIB * (sib_emb[hj] + sib_emb[H + hj]);
  }

  if (tid < 16) TOK[tid] = tokens[t0 + tid];
  __syncthreads();
  for (int t = 0; t < 16; ++t) IN[t][tid] = emb[(int64_t)TOK[t] * H + tid];
  __syncthreads();

  float acc[4][4], sum[4][4];

  // h0 = proj_W @ emb + proj_b
  MATVEC(proj_W, IN, acc);
#pragma unroll
  for (int j = 0; j < 4; ++j) {
    const int hj = hg + 64 * j;
    const float pb = proj_b[hj];
#pragma unroll
    for (int tt = 0; tt < 4; ++tt) {
      const float h0v = acc[j][tt] + pb;
      H0[tg * 4 + tt][hj] = h0v;
      sum[j][tt] = h0v;
    }
  }
  __syncthreads();

  // depth-0 policy
  MATVEC(pol_W1, H0, acc);
#pragma unroll
  for (int j = 0; j < 4; ++j) {
    const int hj = hg + 64 * j;
    const float pb1 = pol_b1[hj], de0 = depth_emb[hj], w2 = pol_w2[hj];
#pragma unroll
    for (int tt = 0; tt < 4; ++tt) {
      const float z = tanhf(acc[j][tt] + pb1 + de0);
      ZW[tg * 4 + tt][hj] = z * w2;
    }
  }
  __syncthreads();
  REDUCE_TO_X(0);
  __syncthreads();

  // depth-0 children base
  MATVEC(child_W, H0, acc);
#pragma unroll
  for (int j = 0; j < 4; ++j) {
    const int hj = hg + 64 * j;
    const float cb = child_b[hj];
#pragma unroll
    for (int tt = 0; tt < 4; ++tt) {
      const float base0 = tanhf(acc[j][tt] + cb);
      B0s[tg * 4 + tt][hj] = base0;
      const float g0 = (X[0][tg * 4 + tt] >= 0.f) ? 1.f : 0.f;
      sum[j][tt] += g0 * (2.f * base0 + sibs[j]);
    }
  }
  __syncthreads();

  // depth-1 policy: polW@base (+ precomputed polW@sib_k)
  float accP[4][4];
  MATVEC(pol_W1, B0s, accP);
#pragma unroll
  for (int k = 0; k < 2; ++k) {
#pragma unroll
    for (int j = 0; j < 4; ++j) {
      const int hj = hg + 64 * j;
      const float pb1 = pol_b1[hj], de1 = depth_emb[H + hj], w2 = pol_w2[hj];
      const float ps = sibproj[k * H + hj];
#pragma unroll
      for (int tt = 0; tt < 4; ++tt) {
        const float z = tanhf(accP[j][tt] + SIB * ps + pb1 + de1);
        ZW[tg * 4 + tt][hj] = z * w2;
      }
    }
    __syncthreads();
    if (k == 0) REDUCE_TO_X(1); else REDUCE_TO_X(2);
    __syncthreads();
  }

  // depth-1 children base + final pooled
  MATVEC(child_W, B0s, acc);
#pragma unroll
  for (int j = 0; j < 4; ++j) {
    const int hj = hg + 64 * j;
    const float cb = child_b[hj];
    const float cs0 = sibproj[2 * H + hj], cs1 = sibproj[3 * H + hj];
#pragma unroll
    for (int tt = 0; tt < 4; ++tt) {
      const int t = tg * 4 + tt;
      const float g0 = (X[0][t] >= 0.f) ? 1.f : 0.f;
      const float m0 = (g0 > 0.f && X[1][t] >= 0.f) ? 1.f : 0.f;
      const float m1 = (g0 > 0.f && X[2][t] >= 0.f) ? 1.f : 0.f;
      const float bk0 = tanhf(acc[j][tt] + SIB * cs0 + cb);
      const float bk1 = tanhf(acc[j][tt] + SIB * cs1 + cb);
      float s = sum[j][tt] + m0 * (2.f * bk0 + sibs[j]) + m1 * (2.f * bk1 + sibs[j]);
      const float cnt = 1.f + 2.f * g0 + 2.f * (m0 + m1);
      const float pooled = s / (cnt + 1e-8f);
      A2[(int64_t)(t0 + t) * K3 + hj] = (_Float16)pooled;
    }
  }
}

// ---------------- big GEMM: C[4096][50257] = A2[4096][256] * B2[50304][256]^T + out_b
// R5-verified skeleton: 128x128 tile, BK=64, double-buffered LDS, counted-vmcnt
// 2-phase pipeline (STAGE(t+1) -> vmcnt(8) -> barrier -> compute -> barrier),
// granule-XOR swizzle via pre-swizzled global source, within-XCD m-chunk-16
// L2 ordering, LDS-transpose epilogue with contiguous 256B nontemporal stores.
// Only change vs R5: K 512 -> 256 (4 K-iters instead of 16).
__global__ __launch_bounds__(256) void k_gemm(const _Float16* __restrict__ A2,
                                              const _Float16* __restrict__ B2,
                                              const float* __restrict__ out_b,
                                              float* __restrict__ C) {
  __shared__ __align__(16) char smem[65536];  // 2 x (At 16KB + Bt 16KB)
  const int tid = threadIdx.x;
  const int lane = tid & 63;
  const int w = tid >> 6;
  const int wg = blockIdx.x;
  const int xcd = wg & 7;
  const int local = wg >> 3;  // [0,1572)
  int gl;
  if (local < 1568) {
    const int mhalf = local / 784;  // 784 = 16*49
    const int r = local % 784;
    const int n_l = r >> 4;   // 0..48
    const int m_in = r & 15;
    gl = n_l * 32 + mhalf * 16 + m_in;
  } else {
    gl = local;
  }
  const int idx = xcd * 1572 + gl;
  const int m0 = (idx & 31) * 128;
  const int n0 = (idx >> 5) * 128;
  f32x4 acc[4][4] = {};

  // staging geometry: per instr a wave writes 8 rows x 64 f16 (1KB linear).
  const int rl = lane >> 3;                 // row within 8-row group
  const int gsw = (lane & 7) ^ rl;          // pre-swizzled source granule
  const _Float16* gA = A2 + (int64_t)(m0 + w * 32 + rl) * K3 + gsw * 8;
  const _Float16* gB = B2 + (int64_t)(n0 + w * 32 + rl) * K3 + gsw * 8;

  const int fr = lane & 15;
  const int g = lane >> 4;                  // K-octet within 32-wide MFMA K
  const int am = (w >> 1) * 64;
  const int bn = (w & 1) * 64;

#define STAGE(c, t)                                                          \
  do {                                                                       \
    _Pragma("unroll") for (int q = 0; q < 4; ++q) {                          \
      gload_lds16(gA + (int64_t)q * 8 * K3 + (t) * 64,                       \
                  (_Float16*)(smem + (c) * 32768) + (w * 32 + q * 8) * 64);  \
      gload_lds16(gB + (int64_t)q * 8 * K3 + (t) * 64,                       \
                  (_Float16*)(smem + (c) * 32768 + 16384) +                  \
                      (w * 32 + q * 8) * 64);                                \
    }                                                                        \
  } while (0)

  STAGE(0, 0);  // 8 loads/thread outstanding

  for (int t = 0; t < 4; ++t) {
    const int cur = t & 1;
    if (t < 3) {
      STAGE(cur ^ 1, t + 1);  // +8 -> 16 outstanding
      asm volatile("s_waitcnt vmcnt(8)" ::: "memory");  // stage(t) complete
    } else {
      asm volatile("s_waitcnt vmcnt(0)" ::: "memory");
    }
    __builtin_amdgcn_s_barrier();          // all waves' stage(t) visible
    __builtin_amdgcn_sched_barrier(0);
    const _Float16* At = (const _Float16*)(smem + cur * 32768);
    const _Float16* Bt = (const _Float16*)(smem + cur * 32768 + 16384);
#pragma unroll
    for (int kk = 0; kk < 2; ++kk) {
      f16x8 af[4], bf[4];
#pragma unroll
      for (int i = 0; i < 4; ++i)
        af[i] = *(const f16x8*)(At + (am + i * 16 + fr) * 64 +
                                (((kk * 4 + g) ^ (fr & 7)) * 8));
#pragma unroll
      for (int i = 0; i < 4; ++i)
        bf[i] = *(const f16x8*)(Bt + (bn + i * 16 + fr) * 64 +
                                (((kk * 4 + g) ^ (fr & 7)) * 8));
#pragma unroll
      for (int i = 0; i < 4; ++i)
#pragma unroll
        for (int j = 0; j < 4; ++j)
          acc[i][j] = __builtin_amdgcn_mfma_f32_16x16x32_f16(af[i], bf[j], acc[i][j], 0, 0, 0);
    }
    __builtin_amdgcn_sched_barrier(0);
    __builtin_amdgcn_s_barrier();          // reads of buf[cur] done -> safe to overwrite
  }

  // ---- epilogue: per m-chunk q, transpose 32x128 f32 through LDS, stream out
  float biasj[4];
#pragma unroll
  for (int j = 0; j < 4; ++j) {
    const int gn = n0 + bn + j * 16 + fr;
    biasj[j] = (gn < VOCAB) ? out_b[gn] : 0.f;
  }
  float* L = (float*)smem;  // [32][132] padded
#pragma unroll
  for (int q = 0; q < 4; ++q) {
#pragma unroll
    for (int j = 0; j < 4; ++j) {
      const int lcol = bn + j * 16 + fr;
#pragma unroll
      for (int r = 0; r < 4; ++r) {
        const int lrow = (w >> 1) * 16 + g * 4 + r;
        L[lrow * 132 + lcol] = acc[q][j][r] + biasj[j];
      }
    }
    __syncthreads();
#pragma unroll
    for (int r8 = 0; r8 < 8; ++r8) {
      const int lr = w * 8 + r8;
      const int gm = m0 + (lr >> 4) * 64 + q * 16 + (lr & 15);
      float* Crow = C + (int64_t)gm * VOCAB + n0;
#pragma unroll
      for (int hh = 0; hh < 2; ++hh) {
        const int c = hh * 64 + lane;
        const float v = L[lr * 132 + c];
        if (n0 + c < VOCAB) __builtin_nontemporal_store(v, Crow + c);
      }
    }
    __syncthreads();
  }
#undef STAGE
}

extern "C" void kernel_launch(void* const* d_in, const int* in_sizes, int n_in,
                              void* d_out, int out_size, void* d_ws, size_t ws_size,
                              hipStream_t stream) {
  const int* tokens = (const int*)d_in[0];
  const float* embedding = (const float*)d_in[1];
  const float* proj_W = (const float*)d_in[2];
  const float* proj_b = (const float*)d_in[3];
  const float* child_W = (const float*)d_in[4];
  const float* child_b = (const float*)d_in[5];
  const float* sib_emb = (const float*)d_in[6];
  const float* depth_emb = (const float*)d_in[7];
  const float* pol_W1 = (const float*)d_in[8];
  const float* pol_b1 = (const float*)d_in[9];
  const float* pol_w2 = (const float*)d_in[10];
  const float* pol_b2 = (const float*)d_in[11];
  const float* out_W = (const float*)d_in[12];
  const float* out_b = (const float*)d_in[13];
  float* C = (float*)d_out;
  char* ws = (char*)d_ws;
  _Float16* B2 = (_Float16*)ws;                              // 50304*256*2 = 25,755,648 B
  _Float16* A2 = (_Float16*)(ws + 25755648);                 // 4096*256*2  =  2,097,152 B
  float* sibproj = (float*)(ws + 25755648 + 2097152);        // 4*256*4 = 4 KB

  k_sib<<<4, 256, 0, stream>>>(pol_W1, child_W, sib_emb, sibproj);
  k_conv<<<2048, 256, 0, stream>>>(out_W, B2);
  k_pooled<<<256, 256, 0, stream>>>(tokens, embedding, proj_W, proj_b, child_W,
                                    child_b, sib_emb, depth_emb, pol_W1, pol_b1,
                                    pol_w2, pol_b2, sibproj, A2);
  k_gemm<<<12576, 256, 0, stream>>>(A2, B2, out_b, C);
}